// Round 1
// baseline (280.100 us; speedup 1.0000x reference)
//
#include <hip/hip_runtime.h>
#include <cstdint>
#include <cstddef>

#define B_ 4
#define T_ 2048
#define C_ 1024
#define M_ (B_ * T_)   // 8192 rows
#define HALF_ 8
#define W_ 17

typedef unsigned short u16;
typedef _Float16 half8 __attribute__((ext_vector_type(8)));
typedef float f32x4 __attribute__((ext_vector_type(4)));

// ---------------- fp32 -> fp16 conversion (vectorized x4) ----------------
__global__ void cvt_f32_f16(const float* __restrict__ in, u16* __restrict__ out, int n4) {
    int i = blockIdx.x * blockDim.x + threadIdx.x;
    if (i >= n4) return;
    float4 v = ((const float4*)in)[i];
    ushort4 o;
    _Float16 a = (_Float16)v.x; o.x = __builtin_bit_cast(unsigned short, a);
    _Float16 b = (_Float16)v.y; o.y = __builtin_bit_cast(unsigned short, b);
    _Float16 c = (_Float16)v.z; o.z = __builtin_bit_cast(unsigned short, c);
    _Float16 d = (_Float16)v.w; o.w = __builtin_bit_cast(unsigned short, d);
    ((ushort4*)out)[i] = o;
}

// ---------------- NT GEMM: C[m][n] = sum_k A[m][k]*B[n][k] + bias[n] ------
// A: M x K fp16 row-major; Bw: N x K fp16 row-major (i.e. weight, so C = A @ Bw^T)
// 128x128 block tile, BK=32, 4 waves each computing 64x64 via 4x4 MFMA 16x16x32.
template <int OUT_F16>
__global__ __launch_bounds__(256) void gemm_nt(
    const u16* __restrict__ A, const u16* __restrict__ Bw,
    const float* __restrict__ bias, void* __restrict__ Cout,
    int Mdim, int Ndim, int Kdim)
{
    __shared__ __align__(16) u16 As[128 * 32];
    __shared__ __align__(16) u16 Bs[128 * 32];

    const int tid  = threadIdx.x;
    const int lane = tid & 63;
    const int wave = tid >> 6;
    const int m0 = blockIdx.y * 128;
    const int n0 = blockIdx.x * 128;
    const int wm = (wave >> 1) * 64;
    const int wn = (wave & 1) * 64;

    // staging: thread i loads rows (m0 + i/4) and (m0 + i/4 + 64), k-chunk (i%4)*8
    const int sr = tid >> 2;
    const int sc = (tid & 3) * 8;
    const u16* Ap = A  + (size_t)(m0 + sr) * Kdim + sc;
    const u16* Bp = Bw + (size_t)(n0 + sr) * Kdim + sc;
    const size_t rowskip = (size_t)64 * Kdim;

    f32x4 zero = {0.f, 0.f, 0.f, 0.f};
    f32x4 acc[4][4];
#pragma unroll
    for (int i = 0; i < 4; ++i)
#pragma unroll
        for (int j = 0; j < 4; ++j) acc[i][j] = zero;

    const int fr = lane & 15;          // row within 16x16 tile for A/B frags
    const int fk = (lane >> 4) * 8;    // k offset within BK=32

    for (int k0 = 0; k0 < Kdim; k0 += 32) {
        uint4 a0 = *(const uint4*)(Ap + k0);
        uint4 a1 = *(const uint4*)(Ap + k0 + rowskip);
        uint4 b0 = *(const uint4*)(Bp + k0);
        uint4 b1 = *(const uint4*)(Bp + k0 + rowskip);
        __syncthreads();
        ((uint4*)As)[tid]        = a0;
        ((uint4*)As)[tid + 256]  = a1;
        ((uint4*)Bs)[tid]        = b0;
        ((uint4*)Bs)[tid + 256]  = b1;
        __syncthreads();

        half8 af[4], bf[4];
#pragma unroll
        for (int i = 0; i < 4; ++i)
            af[i] = *(const half8*)&As[(wm + i * 16 + fr) * 32 + fk];
#pragma unroll
        for (int j = 0; j < 4; ++j)
            bf[j] = *(const half8*)&Bs[(wn + j * 16 + fr) * 32 + fk];
#pragma unroll
        for (int i = 0; i < 4; ++i)
#pragma unroll
            for (int j = 0; j < 4; ++j)
                acc[i][j] = __builtin_amdgcn_mfma_f32_16x16x32_f16(af[i], bf[j], acc[i][j], 0, 0, 0);
    }

    // epilogue: C/D layout col = lane&15, row = (lane>>4)*4 + reg  [m89-verified]
#pragma unroll
    for (int i = 0; i < 4; ++i) {
        const int row0 = m0 + wm + i * 16 + (lane >> 4) * 4;
#pragma unroll
        for (int j = 0; j < 4; ++j) {
            const int col = n0 + wn + j * 16 + (lane & 15);
            const float bv = bias[col];
#pragma unroll
            for (int r = 0; r < 4; ++r) {
                float val = acc[i][j][r] + bv;
                if (OUT_F16) {
                    _Float16 h = (_Float16)val;
                    ((u16*)Cout)[(size_t)(row0 + r) * Ndim + col] = __builtin_bit_cast(unsigned short, h);
                } else {
                    ((float*)Cout)[(size_t)(row0 + r) * Ndim + col] = val;
                }
            }
        }
    }
}

// ---------------- windowed attention: one wave per (b, t) ----------------
__global__ __launch_bounds__(256) void attn_local(
    const u16* __restrict__ q, const u16* __restrict__ k, const u16* __restrict__ v,
    u16* __restrict__ ctx)
{
    const int wid  = blockIdx.x * 4 + (threadIdx.x >> 6);
    const int lane = threadIdx.x & 63;
    const int b = wid >> 11;           // / T_
    const int t = wid & (T_ - 1);
    const size_t rowbase = (size_t)(b * T_ + t) * C_;
    const int c0 = lane * 8;           // lane's channels: [c0, c0+8) and [512+c0, 512+c0+8)

    half8 q0 = *(const half8*)(q + rowbase + c0);
    half8 q1 = *(const half8*)(q + rowbase + 512 + c0);

    float s[W_];
#pragma unroll
    for (int o = 0; o < W_; ++o) {
        int j = t - HALF_ + o;
        if (j >= 0 && j < T_) {
            const size_t kb = (size_t)(b * T_ + j) * C_;
            half8 k0v = *(const half8*)(k + kb + c0);
            half8 k1v = *(const half8*)(k + kb + 512 + c0);
            float d = 0.f;
#pragma unroll
            for (int e = 0; e < 8; ++e)
                d += (float)q0[e] * (float)k0v[e] + (float)q1[e] * (float)k1v[e];
#pragma unroll
            for (int off = 32; off > 0; off >>= 1)
                d += __shfl_xor(d, off);
            s[o] = d * 0.03125f;       // 1/sqrt(1024)
        } else {
            s[o] = -3.0e38f;
        }
    }

    float mx = s[0];
#pragma unroll
    for (int o = 1; o < W_; ++o) mx = fmaxf(mx, s[o]);
    float w[W_];
    float den = 0.f;
#pragma unroll
    for (int o = 0; o < W_; ++o) { w[o] = __expf(s[o] - mx); den += w[o]; }
    const float inv = 1.f / den;

    float acc0[8], acc1[8];
#pragma unroll
    for (int e = 0; e < 8; ++e) { acc0[e] = 0.f; acc1[e] = 0.f; }
#pragma unroll
    for (int o = 0; o < W_; ++o) {
        int j = t - HALF_ + o;
        if (j < 0 || j >= T_) continue;
        const float wt = w[o] * inv;
        const size_t vb_ = (size_t)(b * T_ + j) * C_;
        half8 v0 = *(const half8*)(v + vb_ + c0);
        half8 v1 = *(const half8*)(v + vb_ + 512 + c0);
#pragma unroll
        for (int e = 0; e < 8; ++e) {
            acc0[e] += wt * (float)v0[e];
            acc1[e] += wt * (float)v1[e];
        }
    }

    half8 o0, o1;
#pragma unroll
    for (int e = 0; e < 8; ++e) { o0[e] = (_Float16)acc0[e]; o1[e] = (_Float16)acc1[e]; }
    *(half8*)(ctx + rowbase + c0) = o0;
    *(half8*)(ctx + rowbase + 512 + c0) = o1;
}

// ---------------- host launch ----------------
extern "C" void kernel_launch(void* const* d_in, const int* in_sizes, int n_in,
                              void* d_out, int out_size, void* d_ws, size_t ws_size,
                              hipStream_t stream) {
    const float* x  = (const float*)d_in[0];
    const float* Wq = (const float*)d_in[1];
    const float* bq = (const float*)d_in[2];
    const float* Wk = (const float*)d_in[3];
    const float* bk = (const float*)d_in[4];
    const float* Wv = (const float*)d_in[5];
    const float* bv = (const float*)d_in[6];
    const float* Wo = (const float*)d_in[7];
    const float* bo = (const float*)d_in[8];
    float* out = (float*)d_out;

    u16* xh   = (u16*)d_ws;                       // 8192*1024
    u16* wqh  = xh  + (size_t)M_ * C_;            // 1024*1024 each
    u16* wkh  = wqh + (size_t)C_ * C_;
    u16* wvh  = wkh + (size_t)C_ * C_;
    u16* woh  = wvh + (size_t)C_ * C_;
    u16* qh   = woh + (size_t)C_ * C_;            // 8192*1024 each
    u16* kh   = qh  + (size_t)M_ * C_;
    u16* vh   = kh  + (size_t)M_ * C_;
    u16* ctxh = vh  + (size_t)M_ * C_;
    // total: 5*16.78MB + 4*2.10MB = 92.3 MB of d_ws

    const int nx4 = M_ * C_ / 4;
    const int nw4 = C_ * C_ / 4;
    cvt_f32_f16<<<(nx4 + 255) / 256, 256, 0, stream>>>(x,  xh,  nx4);
    cvt_f32_f16<<<(nw4 + 255) / 256, 256, 0, stream>>>(Wq, wqh, nw4);
    cvt_f32_f16<<<(nw4 + 255) / 256, 256, 0, stream>>>(Wk, wkh, nw4);
    cvt_f32_f16<<<(nw4 + 255) / 256, 256, 0, stream>>>(Wv, wvh, nw4);
    cvt_f32_f16<<<(nw4 + 255) / 256, 256, 0, stream>>>(Wo, woh, nw4);

    dim3 g(C_ / 128, M_ / 128);   // (8, 64)
    gemm_nt<1><<<g, 256, 0, stream>>>(xh, wqh, bq, qh, M_, C_, C_);
    gemm_nt<1><<<g, 256, 0, stream>>>(xh, wkh, bk, kh, M_, C_, C_);
    gemm_nt<1><<<g, 256, 0, stream>>>(xh, wvh, bv, vh, M_, C_, C_);

    attn_local<<<M_ / 4, 256, 0, stream>>>(qh, kh, vh, ctxh);

    gemm_nt<0><<<g, 256, 0, stream>>>(ctxh, woh, bo, out, M_, C_, C_);
}

// Round 2
// 257.959 us; speedup vs baseline: 1.0858x; 1.0858x over previous
//
#include <hip/hip_runtime.h>
#include <cstdint>
#include <cstddef>

#define B_ 4
#define T_ 2048
#define C_ 1024
#define M_ (B_ * T_)   // 8192 rows
#define HALF_ 8
#define W_ 17
#define QKV_STRIDE 3072

typedef unsigned short u16;
typedef _Float16 half8 __attribute__((ext_vector_type(8)));
typedef float f32x4 __attribute__((ext_vector_type(4)));

// ---- async global->LDS, 16B per lane. l is the WAVE-UNIFORM base; HW puts
// lane i at l + i*16B (m104/m108). g is the per-lane global address. ----
__device__ __forceinline__ void gload_lds16(const u16* g, u16* l) {
#if __has_builtin(__builtin_amdgcn_global_load_lds)
    __builtin_amdgcn_global_load_lds(
        (const __attribute__((address_space(1))) void*)g,
        (__attribute__((address_space(3))) void*)l, 16, 0, 0);
#else
    *(uint4*)(l + (threadIdx.x & 63) * 8) = *(const uint4*)g;
#endif
}

// ---------------- fp32 -> fp16 conversion (x4) ----------------
__global__ void cvt_f32_f16(const float* __restrict__ in, u16* __restrict__ out, int n4) {
    int i = blockIdx.x * blockDim.x + threadIdx.x;
    if (i >= n4) return;
    float4 v = ((const float4*)in)[i];
    ushort4 o;
    _Float16 a = (_Float16)v.x; o.x = __builtin_bit_cast(unsigned short, a);
    _Float16 b = (_Float16)v.y; o.y = __builtin_bit_cast(unsigned short, b);
    _Float16 c = (_Float16)v.z; o.z = __builtin_bit_cast(unsigned short, c);
    _Float16 d = (_Float16)v.w; o.w = __builtin_bit_cast(unsigned short, d);
    ((ushort4*)out)[i] = o;
}

// ---- fused Wq/Wk/Wv fp32->fp16 into concatenated (3072 x 1024) buffer ----
__global__ void cvt_wqkv(const float* __restrict__ Wq, const float* __restrict__ Wk,
                         const float* __restrict__ Wv, u16* __restrict__ out) {
    int i = blockIdx.x * 256 + threadIdx.x;     // float4 index, 786432 total
    int sel = blockIdx.x >> 10;                 // 0,1,2 (block-uniform)
    const float* src = (sel == 0) ? Wq : (sel == 1) ? Wk : Wv;
    int j = i - (sel << 18);                    // within-matrix float4 index
    float4 v = ((const float4*)src)[j];
    ushort4 o;
    _Float16 a = (_Float16)v.x; o.x = __builtin_bit_cast(unsigned short, a);
    _Float16 b = (_Float16)v.y; o.y = __builtin_bit_cast(unsigned short, b);
    _Float16 c = (_Float16)v.z; o.z = __builtin_bit_cast(unsigned short, c);
    _Float16 d = (_Float16)v.w; o.w = __builtin_bit_cast(unsigned short, d);
    ((ushort4*)out)[i] = o;
}

__global__ void build_bias(const float* __restrict__ bq, const float* __restrict__ bk,
                           const float* __restrict__ bv, float* __restrict__ bcat) {
    int i = blockIdx.x * 256 + threadIdx.x;     // 3072 total
    const float* src = (i < 1024) ? bq : (i < 2048) ? bk : bv;
    bcat[i] = src[i & 1023];
}

// ---------------- NT GEMM, m97 pattern: global_load_lds width-16 staging ----
// C[m][n] = sum_k A[m][k]*Bw[n][k] + bias[n]; 128x128 tile, BK=32,
// 4 waves x (64x64 via 4x4 MFMA 16x16x32 f16).
template <int OUT_F16>
__global__ __launch_bounds__(256) void gemm_nt_lds(
    const u16* __restrict__ A, const u16* __restrict__ Bw,
    const float* __restrict__ bias, void* __restrict__ Cout,
    int Ndim, int Kdim)
{
    __shared__ __align__(16) u16 As[128 * 32];
    __shared__ __align__(16) u16 Bs[128 * 32];

    const int tid  = threadIdx.x;
    const int lane = tid & 63;
    const int wave = tid >> 6;
    const int m0 = blockIdx.y * 128;
    const int n0 = blockIdx.x * 128;
    const int wm = (wave >> 1) * 64;
    const int wn = (wave & 1) * 64;

    // staging: wave w covers tile rows [w*32, w*32+32); instr q in {0,1} covers
    // rows w*32+q*16 + lane/4, cols (lane&3)*8. LDS dest = wave-uniform base.
    const int srow = wave * 32 + (lane >> 2);
    const int scol = (lane & 3) * 8;
    const u16* Ap = A  + (size_t)(m0 + srow) * Kdim + scol;
    const u16* Bp = Bw + (size_t)(n0 + srow) * Kdim + scol;
    const size_t skip16 = (size_t)16 * Kdim;
    u16* AsW = As + wave * 1024;   // row w*32, col 0
    u16* BsW = Bs + wave * 1024;

    f32x4 zero = {0.f, 0.f, 0.f, 0.f};
    f32x4 acc[4][4];
#pragma unroll
    for (int i = 0; i < 4; ++i)
#pragma unroll
        for (int j = 0; j < 4; ++j) acc[i][j] = zero;

    const int fr = lane & 15;          // row within 16x16 tile
    const int fk = (lane >> 4) * 8;    // k offset within BK=32

    for (int k0 = 0; k0 < Kdim; k0 += 32) {
        __syncthreads();                       // prev tile fully consumed
        gload_lds16(Ap + k0,          AsW);
        gload_lds16(Ap + k0 + skip16, AsW + 512);
        gload_lds16(Bp + k0,          BsW);
        gload_lds16(Bp + k0 + skip16, BsW + 512);
        __syncthreads();                       // drains vmcnt(0); data visible

        half8 af[4], bf[4];
#pragma unroll
        for (int i = 0; i < 4; ++i)
            af[i] = *(const half8*)&As[(wm + i * 16 + fr) * 32 + fk];
#pragma unroll
        for (int j = 0; j < 4; ++j)
            bf[j] = *(const half8*)&Bs[(wn + j * 16 + fr) * 32 + fk];
#pragma unroll
        for (int i = 0; i < 4; ++i)
#pragma unroll
            for (int j = 0; j < 4; ++j)
                acc[i][j] = __builtin_amdgcn_mfma_f32_16x16x32_f16(af[i], bf[j], acc[i][j], 0, 0, 0);
    }

    // epilogue: C/D layout col = lane&15, row = (lane>>4)*4 + reg  [m89]
#pragma unroll
    for (int i = 0; i < 4; ++i) {
        const int row0 = m0 + wm + i * 16 + (lane >> 4) * 4;
#pragma unroll
        for (int j = 0; j < 4; ++j) {
            const int col = n0 + wn + j * 16 + (lane & 15);
            const float bv = bias[col];
#pragma unroll
            for (int r = 0; r < 4; ++r) {
                float val = acc[i][j][r] + bv;
                if (OUT_F16) {
                    _Float16 h = (_Float16)val;
                    ((u16*)Cout)[(size_t)(row0 + r) * Ndim + col] = __builtin_bit_cast(unsigned short, h);
                } else {
                    ((float*)Cout)[(size_t)(row0 + r) * Ndim + col] = val;
                }
            }
        }
    }
}

// ---------------- windowed attention: one wave per (b, t) ----------------
// qkv: (M, 3072) fp16 rows [q | k | v]; ctx out: (M, 1024) fp16
__global__ __launch_bounds__(256) void attn_local(
    const u16* __restrict__ qkv, u16* __restrict__ ctx)
{
    const int wid  = blockIdx.x * 4 + (threadIdx.x >> 6);
    const int lane = threadIdx.x & 63;
    const int b = wid >> 11;           // / T_
    const int t = wid & (T_ - 1);
    const size_t qrow = (size_t)(b * T_ + t) * QKV_STRIDE;
    const int c0 = lane * 8;           // channels [c0,c0+8) and [512+c0, 512+c0+8)

    half8 q0 = *(const half8*)(qkv + qrow + c0);
    half8 q1 = *(const half8*)(qkv + qrow + 512 + c0);

    float s[W_];
#pragma unroll
    for (int o = 0; o < W_; ++o) {
        int j = t - HALF_ + o;
        if (j >= 0 && j < T_) {
            const size_t kb = (size_t)(b * T_ + j) * QKV_STRIDE + 1024;
            half8 k0v = *(const half8*)(qkv + kb + c0);
            half8 k1v = *(const half8*)(qkv + kb + 512 + c0);
            float d = 0.f;
#pragma unroll
            for (int e = 0; e < 8; ++e)
                d += (float)q0[e] * (float)k0v[e] + (float)q1[e] * (float)k1v[e];
#pragma unroll
            for (int off = 32; off > 0; off >>= 1)
                d += __shfl_xor(d, off);
            s[o] = d * 0.03125f;       // 1/sqrt(1024)
        } else {
            s[o] = -3.0e38f;
        }
    }

    float mx = s[0];
#pragma unroll
    for (int o = 1; o < W_; ++o) mx = fmaxf(mx, s[o]);
    float w[W_];
    float den = 0.f;
#pragma unroll
    for (int o = 0; o < W_; ++o) { w[o] = __expf(s[o] - mx); den += w[o]; }
    const float inv = 1.f / den;

    float acc0[8], acc1[8];
#pragma unroll
    for (int e = 0; e < 8; ++e) { acc0[e] = 0.f; acc1[e] = 0.f; }
#pragma unroll
    for (int o = 0; o < W_; ++o) {
        int j = t - HALF_ + o;
        if (j < 0 || j >= T_) continue;
        const float wt = w[o] * inv;
        const size_t vb_ = (size_t)(b * T_ + j) * QKV_STRIDE + 2048;
        half8 v0 = *(const half8*)(qkv + vb_ + c0);
        half8 v1 = *(const half8*)(qkv + vb_ + 512 + c0);
#pragma unroll
        for (int e = 0; e < 8; ++e) {
            acc0[e] += wt * (float)v0[e];
            acc1[e] += wt * (float)v1[e];
        }
    }

    const size_t crow = (size_t)(b * T_ + t) * C_;
    half8 o0, o1;
#pragma unroll
    for (int e = 0; e < 8; ++e) { o0[e] = (_Float16)acc0[e]; o1[e] = (_Float16)acc1[e]; }
    *(half8*)(ctx + crow + c0) = o0;
    *(half8*)(ctx + crow + 512 + c0) = o1;
}

// ---------------- host launch ----------------
extern "C" void kernel_launch(void* const* d_in, const int* in_sizes, int n_in,
                              void* d_out, int out_size, void* d_ws, size_t ws_size,
                              hipStream_t stream) {
    const float* x  = (const float*)d_in[0];
    const float* Wq = (const float*)d_in[1];
    const float* bq = (const float*)d_in[2];
    const float* Wk = (const float*)d_in[3];
    const float* bk = (const float*)d_in[4];
    const float* Wv = (const float*)d_in[5];
    const float* bv = (const float*)d_in[6];
    const float* Wo = (const float*)d_in[7];
    const float* bo = (const float*)d_in[8];
    float* out = (float*)d_out;

    u16* xh   = (u16*)d_ws;                         // 8M elems
    u16* wcat = xh   + (size_t)M_ * C_;             // 3M  (Wq;Wk;Wv)
    u16* woh  = wcat + (size_t)3 * C_ * C_;         // 1M
    u16* qkvh = woh  + (size_t)C_ * C_;             // 24M (M x 3072)
    u16* ctxh = qkvh + (size_t)M_ * QKV_STRIDE;     // 8M
    float* bcat = (float*)(ctxh + (size_t)M_ * C_); // 3072 floats
    // total ~88 MB of d_ws

    const int nx4 = M_ * C_ / 4;
    cvt_f32_f16<<<nx4 / 256, 256, 0, stream>>>(x, xh, nx4);
    cvt_wqkv<<<3 * 1024, 256, 0, stream>>>(Wq, Wk, Wv, wcat);
    cvt_f32_f16<<<1024, 256, 0, stream>>>(Wo, woh, C_ * C_ / 4);
    build_bias<<<12, 256, 0, stream>>>(bq, bk, bv, bcat);

    dim3 gqkv(QKV_STRIDE / 128, M_ / 128);   // (24, 64)
    gemm_nt_lds<1><<<gqkv, 256, 0, stream>>>(xh, wcat, bcat, qkvh, QKV_STRIDE, C_);

    attn_local<<<M_ / 4, 256, 0, stream>>>(qkvh, ctxh);

    dim3 go(C_ / 128, M_ / 128);             // (8, 64)
    gemm_nt_lds<0><<<go, 256, 0, stream>>>(ctxh, woh, bo, out, C_, C_);
}

// Round 3
// 247.088 us; speedup vs baseline: 1.1336x; 1.0440x over previous
//
#include <hip/hip_runtime.h>
#include <cstdint>
#include <cstddef>

#define B_ 4
#define T_ 2048
#define C_ 1024
#define M_ (B_ * T_)   // 8192 rows
#define HALF_ 8
#define W_ 17
#define QKV_STRIDE 3072

typedef unsigned short u16;
typedef _Float16 half8 __attribute__((ext_vector_type(8)));
typedef _Float16 half2_t __attribute__((ext_vector_type(2)));
typedef float f32x4 __attribute__((ext_vector_type(4)));

// ---- async global->LDS, 16B/lane; l is the WAVE-UNIFORM base (m104/m108) ----
__device__ __forceinline__ void gload_lds16(const u16* g, u16* l) {
#if __has_builtin(__builtin_amdgcn_global_load_lds)
    __builtin_amdgcn_global_load_lds(
        (const __attribute__((address_space(1))) void*)g,
        (__attribute__((address_space(3))) void*)l, 16, 0, 0);
#else
    *(uint4*)(l + (threadIdx.x & 63) * 8) = *(const uint4*)g;
#endif
}

__device__ __forceinline__ float dot16(half8 a, half8 b, float acc) {
#if __has_builtin(__builtin_amdgcn_fdot2)
    const half2_t* pa = (const half2_t*)&a;
    const half2_t* pb = (const half2_t*)&b;
#pragma unroll
    for (int e = 0; e < 4; ++e) acc = __builtin_amdgcn_fdot2(pa[e], pb[e], acc, false);
#else
#pragma unroll
    for (int e = 0; e < 8; ++e) acc += (float)a[e] * (float)b[e];
#endif
    return acc;
}

// ---------------- fused prologue: all fp32->fp16 conversions + bias concat ----
// blocks [0,8192): x -> xh            (2M float4)
// blocks [8192,11264): Wq|Wk|Wv -> wcat (3K x 1K)
// blocks [11264,12288): Wo -> woh
// blocks [12288,12300): bq|bk|bv -> bcat (3072 floats)
__global__ void prologue(const float* __restrict__ x,
                         const float* __restrict__ Wq, const float* __restrict__ Wk,
                         const float* __restrict__ Wv, const float* __restrict__ Wo,
                         const float* __restrict__ bq, const float* __restrict__ bk,
                         const float* __restrict__ bv,
                         u16* __restrict__ xh, u16* __restrict__ wcat,
                         u16* __restrict__ woh, float* __restrict__ bcat) {
    const int blk = blockIdx.x;
    if (blk >= 12288) {   // bias concat
        int i = (blk - 12288) * 256 + threadIdx.x;     // 0..3071
        const float* src = (i < 1024) ? bq : (i < 2048) ? bk : bv;
        bcat[i] = src[i & 1023];
        return;
    }
    const float* src;
    u16* dst;
    int j;
    if (blk < 8192)       { src = x;  dst = xh;   j = blk * 256 + threadIdx.x; }
    else if (blk < 11264) {
        int bb = blk - 8192;
        int sel = bb >> 10;                            // 0,1,2 block-uniform
        src = (sel == 0) ? Wq : (sel == 1) ? Wk : Wv;
        dst = wcat + ((size_t)sel << 20);              // sel * 1M halves
        j = (bb - (sel << 10)) * 256 + threadIdx.x;
    } else                { src = Wo; dst = woh;  j = (blk - 11264) * 256 + threadIdx.x; }
    float4 v = ((const float4*)src)[j];
    ushort4 o;
    _Float16 a = (_Float16)v.x; o.x = __builtin_bit_cast(unsigned short, a);
    _Float16 b = (_Float16)v.y; o.y = __builtin_bit_cast(unsigned short, b);
    _Float16 c = (_Float16)v.z; o.z = __builtin_bit_cast(unsigned short, c);
    _Float16 d = (_Float16)v.w; o.w = __builtin_bit_cast(unsigned short, d);
    ((ushort4*)dst)[j] = o;
}

// ---------------- NT GEMM, m97 pattern + XOR bank swizzle ----
// C[m][n] = sum_k A[m][k]*Bw[n][k] + bias[n]; 128x128 tile, BK=32,
// 4 waves x (64x64 via 4x4 MFMA 16x16x32 f16).
// Swizzle: staging lane fetches global k-chunk (lane&3)^((row>>1)&3) into fixed
// LDS slot lane&3; reader computes slot p = (lane>>4)^((lane>>1)&3) -> spreads
// ds_read_b128 across all 32 banks (2-way only, free per m136).
template <int OUT_F16>
__global__ __launch_bounds__(256) void gemm_nt_lds(
    const u16* __restrict__ A, const u16* __restrict__ Bw,
    const float* __restrict__ bias, void* __restrict__ Cout,
    int Ndim, int Kdim)
{
    __shared__ __align__(16) u16 As[128 * 32];
    __shared__ __align__(16) u16 Bs[128 * 32];

    const int tid  = threadIdx.x;
    const int lane = tid & 63;
    const int wave = tid >> 6;
    const int m0 = blockIdx.y * 128;
    const int n0 = blockIdx.x * 128;
    const int wm = (wave >> 1) * 64;
    const int wn = (wave & 1) * 64;

    // staging: wave w rows [w*32, w*32+32); lane covers row w*32+(lane>>2),
    // LDS slot lane&3; global chunk XOR-swizzled by (row>>1)&3 = (lane>>3)&3.
    const int srow = wave * 32 + (lane >> 2);
    const int kc = ((lane & 3) ^ ((lane >> 3) & 3)) * 8;
    const u16* Ap = A  + (size_t)(m0 + srow) * Kdim + kc;
    const u16* Bp = Bw + (size_t)(n0 + srow) * Kdim + kc;
    const size_t skip16 = (size_t)16 * Kdim;   // rows+16: swizzle unchanged (mod-4)
    u16* AsW = As + wave * 1024;
    u16* BsW = Bs + wave * 1024;

    f32x4 zero = {0.f, 0.f, 0.f, 0.f};
    f32x4 acc[4][4];
#pragma unroll
    for (int i = 0; i < 4; ++i)
#pragma unroll
        for (int j = 0; j < 4; ++j) acc[i][j] = zero;

    const int fr = lane & 15;                                  // row in 16x16 tile
    const int fk = (((lane >> 4) ^ ((lane >> 1) & 3)) & 3) * 8; // swizzled LDS slot

    for (int k0 = 0; k0 < Kdim; k0 += 32) {
        __syncthreads();
        gload_lds16(Ap + k0,          AsW);
        gload_lds16(Ap + k0 + skip16, AsW + 512);
        gload_lds16(Bp + k0,          BsW);
        gload_lds16(Bp + k0 + skip16, BsW + 512);
        __syncthreads();

        half8 af[4], bf[4];
#pragma unroll
        for (int i = 0; i < 4; ++i)
            af[i] = *(const half8*)&As[(wm + i * 16 + fr) * 32 + fk];
#pragma unroll
        for (int j = 0; j < 4; ++j)
            bf[j] = *(const half8*)&Bs[(wn + j * 16 + fr) * 32 + fk];
#pragma unroll
        for (int i = 0; i < 4; ++i)
#pragma unroll
            for (int j = 0; j < 4; ++j)
                acc[i][j] = __builtin_amdgcn_mfma_f32_16x16x32_f16(af[i], bf[j], acc[i][j], 0, 0, 0);
    }

    // epilogue: C/D layout col = lane&15, row = (lane>>4)*4 + reg  [m89]
#pragma unroll
    for (int i = 0; i < 4; ++i) {
        const int row0 = m0 + wm + i * 16 + (lane >> 4) * 4;
#pragma unroll
        for (int j = 0; j < 4; ++j) {
            const int col = n0 + wn + j * 16 + (lane & 15);
            const float bv = bias[col];
#pragma unroll
            for (int r = 0; r < 4; ++r) {
                float val = acc[i][j][r] + bv;
                if (OUT_F16) {
                    _Float16 h = (_Float16)val;
                    ((u16*)Cout)[(size_t)(row0 + r) * Ndim + col] = __builtin_bit_cast(unsigned short, h);
                } else {
                    ((float*)Cout)[(size_t)(row0 + r) * Ndim + col] = val;
                }
            }
        }
    }
}

// ---------------- windowed attention: one wave per (b, t), branchless ----
// qkv: (M, 3072) fp16 rows [q | k | v]; ctx out: (M, 1024) fp16
__global__ __launch_bounds__(256) void attn_local(
    const u16* __restrict__ qkv, u16* __restrict__ ctx)
{
    const int wid  = blockIdx.x * 4 + (threadIdx.x >> 6);
    const int lane = threadIdx.x & 63;
    const int b = wid >> 11;
    const int t = wid & (T_ - 1);
    const int base = b * T_;
    const size_t qrow = (size_t)(base + t) * QKV_STRIDE;
    const int c0 = lane * 8;

    half8 q0 = *(const half8*)(qkv + qrow + c0);
    half8 q1 = *(const half8*)(qkv + qrow + 512 + c0);

    float s[W_];
#pragma unroll
    for (int o = 0; o < W_; ++o) {
        int j = t - HALF_ + o;
        int jc = min(max(j, 0), T_ - 1);              // clamped: loads always valid
        const size_t kb = (size_t)(base + jc) * QKV_STRIDE + 1024;
        half8 k0v = *(const half8*)(qkv + kb + c0);
        half8 k1v = *(const half8*)(qkv + kb + 512 + c0);
        float d = dot16(q1, k1v, dot16(q0, k0v, 0.f));
#pragma unroll
        for (int off = 32; off > 0; off >>= 1)
            d += __shfl_xor(d, off);
        s[o] = (j == jc) ? d * 0.03125f : -3.0e38f;   // mask, no divergent loads
    }

    float mx = s[0];
#pragma unroll
    for (int o = 1; o < W_; ++o) mx = fmaxf(mx, s[o]);
    float den = 0.f;
#pragma unroll
    for (int o = 0; o < W_; ++o) den += __expf(s[o] - mx);
    const float inv = 1.f / den;

    float acc0[8], acc1[8];
#pragma unroll
    for (int e = 0; e < 8; ++e) { acc0[e] = 0.f; acc1[e] = 0.f; }
#pragma unroll
    for (int o = 0; o < W_; ++o) {
        int j = t - HALF_ + o;
        int jc = min(max(j, 0), T_ - 1);
        const float wt = __expf(s[o] - mx) * inv;     // 0 for masked taps
        const size_t vb_ = (size_t)(base + jc) * QKV_STRIDE + 2048;
        half8 v0 = *(const half8*)(qkv + vb_ + c0);
        half8 v1 = *(const half8*)(qkv + vb_ + 512 + c0);
#pragma unroll
        for (int e = 0; e < 8; ++e) {
            acc0[e] += wt * (float)v0[e];
            acc1[e] += wt * (float)v1[e];
        }
    }

    const size_t crow = (size_t)(base + t) * C_;
    half8 o0, o1;
#pragma unroll
    for (int e = 0; e < 8; ++e) { o0[e] = (_Float16)acc0[e]; o1[e] = (_Float16)acc1[e]; }
    *(half8*)(ctx + crow + c0) = o0;
    *(half8*)(ctx + crow + 512 + c0) = o1;
}

// ---------------- host launch ----------------
extern "C" void kernel_launch(void* const* d_in, const int* in_sizes, int n_in,
                              void* d_out, int out_size, void* d_ws, size_t ws_size,
                              hipStream_t stream) {
    const float* x  = (const float*)d_in[0];
    const float* Wq = (const float*)d_in[1];
    const float* bq = (const float*)d_in[2];
    const float* Wk = (const float*)d_in[3];
    const float* bk = (const float*)d_in[4];
    const float* Wv = (const float*)d_in[5];
    const float* bv = (const float*)d_in[6];
    const float* Wo = (const float*)d_in[7];
    const float* bo = (const float*)d_in[8];
    float* out = (float*)d_out;

    u16* xh   = (u16*)d_ws;                         // 8M halves
    u16* wcat = xh   + (size_t)M_ * C_;             // 3M  (Wq;Wk;Wv)
    u16* woh  = wcat + (size_t)3 * C_ * C_;         // 1M
    u16* qkvh = woh  + (size_t)C_ * C_;             // 24M (M x 3072)
    u16* ctxh = qkvh + (size_t)M_ * QKV_STRIDE;     // 8M
    float* bcat = (float*)(ctxh + (size_t)M_ * C_); // 3072 floats

    prologue<<<12300, 256, 0, stream>>>(x, Wq, Wk, Wv, Wo, bq, bk, bv,
                                        xh, wcat, woh, bcat);

    dim3 gqkv(QKV_STRIDE / 128, M_ / 128);   // (24, 64)
    gemm_nt_lds<1><<<gqkv, 256, 0, stream>>>(xh, wcat, bcat, qkvh, QKV_STRIDE, C_);

    attn_local<<<M_ / 4, 256, 0, stream>>>(qkvh, ctxh);

    dim3 go(C_ / 128, M_ / 128);             // (8, 64)
    gemm_nt_lds<0><<<go, 256, 0, stream>>>(ctxh, woh, bo, out, C_, C_);
}

// Round 4
// 232.848 us; speedup vs baseline: 1.2029x; 1.0612x over previous
//
#include <hip/hip_runtime.h>
#include <cstdint>
#include <cstddef>

#define B_ 4
#define T_ 2048
#define C_ 1024
#define M_ (B_ * T_)   // 8192 rows
#define HALF_ 8
#define W_ 17
#define QKV_STRIDE 3072

typedef unsigned short u16;
typedef _Float16 half8 __attribute__((ext_vector_type(8)));
typedef _Float16 half2_t __attribute__((ext_vector_type(2)));
typedef float f32x16 __attribute__((ext_vector_type(16)));

// ---- async global->LDS, 16B/lane; l is the WAVE-UNIFORM base (m104/m108) ----
__device__ __forceinline__ void gload_lds16(const u16* g, u16* l) {
#if __has_builtin(__builtin_amdgcn_global_load_lds)
    __builtin_amdgcn_global_load_lds(
        (const __attribute__((address_space(1))) void*)g,
        (__attribute__((address_space(3))) void*)l, 16, 0, 0);
#else
    *(uint4*)(l + (threadIdx.x & 63) * 8) = *(const uint4*)g;
#endif
}

__device__ __forceinline__ float dot16(half8 a, half8 b, float acc) {
#if __has_builtin(__builtin_amdgcn_fdot2)
    const half2_t* pa = (const half2_t*)&a;
    const half2_t* pb = (const half2_t*)&b;
#pragma unroll
    for (int e = 0; e < 4; ++e) acc = __builtin_amdgcn_fdot2(pa[e], pb[e], acc, false);
#else
#pragma unroll
    for (int e = 0; e < 8; ++e) acc += (float)a[e] * (float)b[e];
#endif
    return acc;
}

// ---------------- fused prologue: all fp32->fp16 conversions + bias concat ----
__global__ void prologue(const float* __restrict__ x,
                         const float* __restrict__ Wq, const float* __restrict__ Wk,
                         const float* __restrict__ Wv, const float* __restrict__ Wo,
                         const float* __restrict__ bq, const float* __restrict__ bk,
                         const float* __restrict__ bv,
                         u16* __restrict__ xh, u16* __restrict__ wcat,
                         u16* __restrict__ woh, float* __restrict__ bcat) {
    const int blk = blockIdx.x;
    if (blk >= 12288) {   // bias concat
        int i = (blk - 12288) * 256 + threadIdx.x;     // 0..3071
        const float* src = (i < 1024) ? bq : (i < 2048) ? bk : bv;
        bcat[i] = src[i & 1023];
        return;
    }
    const float* src;
    u16* dst;
    int j;
    if (blk < 8192)       { src = x;  dst = xh;   j = blk * 256 + threadIdx.x; }
    else if (blk < 11264) {
        int bb = blk - 8192;
        int sel = bb >> 10;                            // 0,1,2 block-uniform
        src = (sel == 0) ? Wq : (sel == 1) ? Wk : Wv;
        dst = wcat + ((size_t)sel << 20);
        j = (bb - (sel << 10)) * 256 + threadIdx.x;
    } else                { src = Wo; dst = woh;  j = (blk - 11264) * 256 + threadIdx.x; }
    float4 v = ((const float4*)src)[j];
    ushort4 o;
    _Float16 a = (_Float16)v.x; o.x = __builtin_bit_cast(unsigned short, a);
    _Float16 b = (_Float16)v.y; o.y = __builtin_bit_cast(unsigned short, b);
    _Float16 c = (_Float16)v.z; o.z = __builtin_bit_cast(unsigned short, c);
    _Float16 d = (_Float16)v.w; o.w = __builtin_bit_cast(unsigned short, d);
    ((ushort4*)dst)[j] = o;
}

// ---------------- NT GEMM: 128x128 tile, BK=32, mfma_f32_32x32x16_f16 ----
// 4 waves x (64x64 via 2x2 of 32x32). XOR bank swizzle kept (re-derived for
// 32x32 frag addressing; lanes 0-7 of each ds_read_b128 cover all 32 banks).
// Layouts [m74/m101-verified family]:
//   A-frag: m = lane&31, k = (lane>>5)*8 + j  (within K=16 step)
//   C/D:    col = lane&31, row = (reg&3) + 8*(reg>>2) + 4*(lane>>5)
template <int OUT_F16>
__global__ __launch_bounds__(256) void gemm_nt_lds(
    const u16* __restrict__ A, const u16* __restrict__ Bw,
    const float* __restrict__ bias, void* __restrict__ Cout,
    int Ndim, int Kdim)
{
    __shared__ __align__(16) u16 As[128 * 32];
    __shared__ __align__(16) u16 Bs[128 * 32];

    const int tid  = threadIdx.x;
    const int lane = tid & 63;
    const int wave = tid >> 6;
    const int m0 = blockIdx.y * 128;
    const int n0 = blockIdx.x * 128;
    const int wm = (wave >> 1) * 64;
    const int wn = (wave & 1) * 64;

    // staging: wave w rows [w*32, w*32+32); lane -> row w*32+(lane>>2),
    // LDS slot lane&3 holds global chunk (lane&3)^((row>>1)&3).
    const int srow = wave * 32 + (lane >> 2);
    const int kc = ((lane & 3) ^ ((lane >> 3) & 3)) * 8;
    const u16* Ap = A  + (size_t)(m0 + srow) * Kdim + kc;
    const u16* Bp = Bw + (size_t)(n0 + srow) * Kdim + kc;
    const size_t skip16 = (size_t)16 * Kdim;
    u16* AsW = As + wave * 1024;
    u16* BsW = Bs + wave * 1024;

    f32x16 acc[2][2];
#pragma unroll
    for (int i = 0; i < 2; ++i)
#pragma unroll
        for (int j = 0; j < 2; ++j)
#pragma unroll
            for (int r = 0; r < 16; ++r) acc[i][j][r] = 0.f;

    const int rr = lane & 31;          // row within 32x32 tile
    const int hi = lane >> 5;          // k half-select within K=16
    const int sw = (lane >> 1) & 3;    // row-derived swizzle term

    for (int k0 = 0; k0 < Kdim; k0 += 32) {
        __syncthreads();
        gload_lds16(Ap + k0,          AsW);
        gload_lds16(Ap + k0 + skip16, AsW + 512);
        gload_lds16(Bp + k0,          BsW);
        gload_lds16(Bp + k0 + skip16, BsW + 512);
        __syncthreads();

#pragma unroll
        for (int kk = 0; kk < 2; ++kk) {      // two K=16 steps per BK=32
            const int slot = ((kk * 2 + hi) ^ sw) * 8;   // swizzled 8-half chunk
            half8 af[2], bf[2];
#pragma unroll
            for (int i = 0; i < 2; ++i)
                af[i] = *(const half8*)&As[(wm + i * 32 + rr) * 32 + slot];
#pragma unroll
            for (int j = 0; j < 2; ++j)
                bf[j] = *(const half8*)&Bs[(wn + j * 32 + rr) * 32 + slot];
#pragma unroll
            for (int i = 0; i < 2; ++i)
#pragma unroll
                for (int j = 0; j < 2; ++j)
                    acc[i][j] = __builtin_amdgcn_mfma_f32_32x32x16_f16(af[i], bf[j], acc[i][j], 0, 0, 0);
        }
    }

    // epilogue: col = lane&31, row = (reg&3) + 8*(reg>>2) + 4*(lane>>5)
#pragma unroll
    for (int i = 0; i < 2; ++i) {
#pragma unroll
        for (int j = 0; j < 2; ++j) {
            const int col = n0 + wn + j * 32 + (lane & 31);
            const float bv = bias[col];
#pragma unroll
            for (int reg = 0; reg < 16; ++reg) {
                const int row = m0 + wm + i * 32 + (reg & 3) + 8 * (reg >> 2) + 4 * (lane >> 5);
                float val = acc[i][j][reg] + bv;
                if (OUT_F16) {
                    _Float16 h = (_Float16)val;
                    ((u16*)Cout)[(size_t)row * Ndim + col] = __builtin_bit_cast(unsigned short, h);
                } else {
                    ((float*)Cout)[(size_t)row * Ndim + col] = val;
                }
            }
        }
    }
}

// ---------------- windowed attention: one wave per TWO tokens (t0, t0+1) ----
// Shares the 18 k/v rows between the two tokens: 40 row-reads per 2 tokens
// instead of 70. qkv: (M, 3072) fp16 [q|k|v]; ctx: (M, 1024) fp16.
__global__ __launch_bounds__(256) void attn_local(
    const u16* __restrict__ qkv, u16* __restrict__ ctx)
{
    const int wid  = blockIdx.x * 4 + (threadIdx.x >> 6);   // 4096 waves
    const int lane = threadIdx.x & 63;
    const int b  = wid >> 10;
    const int t0 = (wid & 1023) * 2;
    const int base = b * T_;
    const int c0 = lane * 8;

    const size_t q0row = (size_t)(base + t0) * QKV_STRIDE;
    const size_t q1row = q0row + QKV_STRIDE;
    half8 qa0 = *(const half8*)(qkv + q0row + c0);
    half8 qa1 = *(const half8*)(qkv + q0row + 512 + c0);
    half8 qb0 = *(const half8*)(qkv + q1row + c0);
    half8 qb1 = *(const half8*)(qkv + q1row + 512 + c0);

    float s0[W_], s1[W_];
#pragma unroll
    for (int r = 0; r < W_ + 1; ++r) {             // rows t0-8 .. t0+9
        int j  = t0 - HALF_ + r;
        int jc = min(max(j, 0), T_ - 1);
        const size_t kb = (size_t)(base + jc) * QKV_STRIDE + 1024;
        half8 k0 = *(const half8*)(qkv + kb + c0);
        half8 k1 = *(const half8*)(qkv + kb + 512 + c0);
        float d0 = dot16(qa1, k1, dot16(qa0, k0, 0.f));
        float d1 = dot16(qb1, k1, dot16(qb0, k0, 0.f));
#pragma unroll
        for (int off = 32; off > 0; off >>= 1) {
            d0 += __shfl_xor(d0, off);
            d1 += __shfl_xor(d1, off);
        }
        const bool ok = (j == jc);
        if (r < W_)  s0[r]     = ok ? d0 * 0.03125f : -3.0e38f;
        if (r >= 1)  s1[r - 1] = ok ? d1 * 0.03125f : -3.0e38f;
    }

    float mx0 = s0[0], mx1 = s1[0];
#pragma unroll
    for (int o = 1; o < W_; ++o) { mx0 = fmaxf(mx0, s0[o]); mx1 = fmaxf(mx1, s1[o]); }
    float den0 = 0.f, den1 = 0.f;
#pragma unroll
    for (int o = 0; o < W_; ++o) { den0 += __expf(s0[o] - mx0); den1 += __expf(s1[o] - mx1); }
    const float inv0 = 1.f / den0, inv1 = 1.f / den1;

    float acc0[16], acc1[16];
#pragma unroll
    for (int e = 0; e < 16; ++e) { acc0[e] = 0.f; acc1[e] = 0.f; }

#pragma unroll
    for (int r = 0; r < W_ + 1; ++r) {
        int j  = t0 - HALF_ + r;
        int jc = min(max(j, 0), T_ - 1);
        const float w0 = (r < W_)  ? __expf(s0[r]     - mx0) * inv0 : 0.f;  // masked -> 0
        const float w1 = (r >= 1)  ? __expf(s1[r - 1] - mx1) * inv1 : 0.f;
        const size_t vb_ = (size_t)(base + jc) * QKV_STRIDE + 2048;
        half8 v0 = *(const half8*)(qkv + vb_ + c0);
        half8 v1 = *(const half8*)(qkv + vb_ + 512 + c0);
#pragma unroll
        for (int e = 0; e < 8; ++e) {
            acc0[e]     += w0 * (float)v0[e];
            acc0[e + 8] += w0 * (float)v1[e];
            acc1[e]     += w1 * (float)v0[e];
            acc1[e + 8] += w1 * (float)v1[e];
        }
    }

    const size_t c0row = (size_t)(base + t0) * C_;
    const size_t c1row = c0row + C_;
    half8 o0, o1, o2, o3;
#pragma unroll
    for (int e = 0; e < 8; ++e) {
        o0[e] = (_Float16)acc0[e];  o1[e] = (_Float16)acc0[e + 8];
        o2[e] = (_Float16)acc1[e];  o3[e] = (_Float16)acc1[e + 8];
    }
    *(half8*)(ctx + c0row + c0) = o0;
    *(half8*)(ctx + c0row + 512 + c0) = o1;
    *(half8*)(ctx + c1row + c0) = o2;
    *(half8*)(ctx + c1row + 512 + c0) = o3;
}

// ---------------- host launch ----------------
extern "C" void kernel_launch(void* const* d_in, const int* in_sizes, int n_in,
                              void* d_out, int out_size, void* d_ws, size_t ws_size,
                              hipStream_t stream) {
    const float* x  = (const float*)d_in[0];
    const float* Wq = (const float*)d_in[1];
    const float* bq = (const float*)d_in[2];
    const float* Wk = (const float*)d_in[3];
    const float* bk = (const float*)d_in[4];
    const float* Wv = (const float*)d_in[5];
    const float* bv = (const float*)d_in[6];
    const float* Wo = (const float*)d_in[7];
    const float* bo = (const float*)d_in[8];
    float* out = (float*)d_out;

    u16* xh   = (u16*)d_ws;                         // 8M halves
    u16* wcat = xh   + (size_t)M_ * C_;             // 3M  (Wq;Wk;Wv)
    u16* woh  = wcat + (size_t)3 * C_ * C_;         // 1M
    u16* qkvh = woh  + (size_t)C_ * C_;             // 24M (M x 3072)
    u16* ctxh = qkvh + (size_t)M_ * QKV_STRIDE;     // 8M
    float* bcat = (float*)(ctxh + (size_t)M_ * C_); // 3072 floats

    prologue<<<12300, 256, 0, stream>>>(x, Wq, Wk, Wv, Wo, bq, bk, bv,
                                        xh, wcat, woh, bcat);

    dim3 gqkv(QKV_STRIDE / 128, M_ / 128);   // (24, 64)
    gemm_nt_lds<1><<<gqkv, 256, 0, stream>>>(xh, wcat, bcat, qkvh, QKV_STRIDE, C_);

    attn_local<<<M_ / 8, 256, 0, stream>>>(qkvh, ctxh);   // 1024 blocks

    dim3 go(C_ / 128, M_ / 128);             // (8, 64)
    gemm_nt_lds<0><<<go, 256, 0, stream>>>(ctxh, woh, bo, out, C_, C_);
}